// Round 1
// baseline (119.476 us; speedup 1.0000x reference)
//
#include <hip/hip_runtime.h>

// SpikeAmplifier: T=128, N=16, C=1, J=8192.
// recurrence per element (n,c,j), sequential over t:
//   h = y_prev*h + w*y_prev;  x = x_t + h;  v = v + x;
//   s = (v >= 1);  v = s ? 0 : v;  out[t] = s;  y_prev = s
// Memory-bound streaming: 64 MiB in + 64 MiB out.

#define T_STEPS 128
#define J_DIM   8192
#define NCJ     131072   // N*C*J = 16*1*8192 — per-timestep element count & t-stride

__global__ __launch_bounds__(256) void SpikeAmplifier_73452530696745_kernel(
    const float* __restrict__ in,    // (T, N, C, J) fp32
    const float* __restrict__ w,     // (J,) fp32
    float* __restrict__ out)         // (T, N, C, J) fp32 spikes
{
    const int idx = blockIdx.x * blockDim.x + threadIdx.x;   // 0 .. NCJ-1
    const float wj = w[idx & (J_DIM - 1)];

    float h = 0.0f, y = 0.0f, v = 0.0f;
    int off = idx;

    // Loads at each t are independent of the compute chain (address = idx + t*NCJ),
    // so unrolling lets the compiler batch 8 global_load_dword in flight per wave
    // before the dependent VALU chain — needed to hit ~10 B/cyc/CU at ~900 cy latency.
    #pragma unroll 8
    for (int t = 0; t < T_STEPS; ++t) {
        const float xt = in[off];

        // y ∈ {0,1} ⇒ both products are exact; fma contraction cannot change the result.
        h = y * h + wj * y;

        // Match reference rounding order exactly: x = x_t + h; v = v + x.
        const float x = xt + h;
        v = v + x;

        const bool s = (v >= 1.0f);   // sign-equivalent to (v - 1.0f) >= 0
        y = s ? 1.0f : 0.0f;
        v = s ? 0.0f : v;

        out[off] = y;
        off += NCJ;
    }
}

extern "C" void kernel_launch(void* const* d_in, const int* in_sizes, int n_in,
                              void* d_out, int out_size, void* d_ws, size_t ws_size,
                              hipStream_t stream) {
    const float* in  = (const float*)d_in[0];   // (T,N,C,J) = 16,777,216 floats
    const float* w   = (const float*)d_in[1];   // (J,) = 8192 floats
    float*       out = (float*)d_out;           // (T,N,C,J)

    // 131072 threads = 512 blocks x 256 = 2048 waves = 8 waves/CU.
    SpikeAmplifier_73452530696745_kernel<<<NCJ / 256, 256, 0, stream>>>(in, w, out);
}

// Round 2
// 118.890 us; speedup vs baseline: 1.0049x; 1.0049x over previous
//
#include <hip/hip_runtime.h>

// SpikeAmplifier: T=128, N=16, C=1, J=8192.
// Per-element (n,c,j) serial recurrence over t:
//   h = y*h + w*y;  x = x_t + h;  v = v + x;
//   s = (v >= 1);  v = s ? 0 : v;  out[t] = s;  y = s
// Pure streaming, memory-bound: 64 MiB in + 64 MiB out. Roofline ~21 us @ 6.3 TB/s.
//
// R1 change: explicit register double-buffer (prefetch next 16 t-steps before
// computing current 16) so >=16 dword loads/lane are in flight during the
// dependent compute chain — decouples the load stream from the vmcnt-ordered
// store stream that #pragma unroll alone interleaved. Nontemporal hints on the
// streaming load/store paths (zero reuse).

#define T_STEPS 128
#define J_DIM   8192
#define NCJ     131072   // N*C*J — per-timestep element count & t-stride (elements)
#define U       16       // prefetch depth (t-steps per block)

__global__ __launch_bounds__(256) void SpikeAmplifier_73452530696745_kernel(
    const float* __restrict__ in,    // (T, N, C, J) fp32
    const float* __restrict__ w,     // (J,) fp32
    float* __restrict__ out)         // (T, N, C, J) fp32 spikes
{
    const int idx = blockIdx.x * blockDim.x + threadIdx.x;   // 0 .. NCJ-1
    const float wj = w[idx & (J_DIM - 1)];

    float h = 0.0f, y = 0.0f, v = 0.0f;

    // Prologue: fetch block 0.
    float xbuf[U];
    int off = idx;
    #pragma unroll
    for (int u = 0; u < U; ++u)
        xbuf[u] = __builtin_nontemporal_load(&in[off + u * NCJ]);

    constexpr int NBLK = T_STEPS / U;   // 8
    for (int blk = 0; blk < NBLK; ++blk) {
        // Prefetch block blk+1 BEFORE any compute/store of block blk:
        // these 16 loads issue into the vm queue ahead of the dependent chain,
        // giving 4 KiB/wave in flight while the ALU chain runs.
        float xnext[U];
        const int nextbase = off + U * NCJ;
        if (blk + 1 < NBLK) {
            #pragma unroll
            for (int u = 0; u < U; ++u)
                xnext[u] = __builtin_nontemporal_load(&in[nextbase + u * NCJ]);
        }

        // Compute + store current block. Arithmetic order matches reference
        // exactly (y in {0,1} makes h's fma contraction exact; x then v adds
        // are in reference order; v>=1.0f is sign-equivalent to v-1>=0).
        #pragma unroll
        for (int u = 0; u < U; ++u) {
            h = y * h + wj * y;
            const float x = xbuf[u] + h;
            v = v + x;
            const bool s = (v >= 1.0f);
            y = s ? 1.0f : 0.0f;
            v = s ? 0.0f : v;
            __builtin_nontemporal_store(y, &out[off + u * NCJ]);
        }

        off = nextbase;
        #pragma unroll
        for (int u = 0; u < U; ++u) xbuf[u] = xnext[u];
    }
}

extern "C" void kernel_launch(void* const* d_in, const int* in_sizes, int n_in,
                              void* d_out, int out_size, void* d_ws, size_t ws_size,
                              hipStream_t stream) {
    const float* in  = (const float*)d_in[0];   // (T,N,C,J) = 16,777,216 floats
    const float* w   = (const float*)d_in[1];   // (J,) = 8192 floats
    float*       out = (float*)d_out;           // (T,N,C,J)

    // 131072 threads = 512 blocks x 256 = 2048 waves = 8 waves/CU.
    SpikeAmplifier_73452530696745_kernel<<<NCJ / 256, 256, 0, stream>>>(in, w, out);
}